// Round 1
// baseline (263.049 us; speedup 1.0000x reference)
//
#include <hip/hip_runtime.h>
#include <math.h>

typedef float f32x4 __attribute__((ext_vector_type(4)));
typedef short s16x8 __attribute__((ext_vector_type(8)));
typedef short s16x4 __attribute__((ext_vector_type(4)));

__device__ inline short f2bf(float f) {
    unsigned u = __float_as_uint(f);
    u = (u + 0x7fffu + ((u >> 16) & 1u)) >> 16;  // RNE
    return (short)(unsigned short)u;
}
__device__ inline float bf2f(short s) {
    return __uint_as_float(((unsigned)(unsigned short)s) << 16);
}

// ---------------------------------------------------------------------------
// Kernel 1: pack weights -> WallT[n][k] bf16, n in [0,384) = f|g|h cols, k in [0,256)
// ---------------------------------------------------------------------------
__global__ __launch_bounds__(256) void wconv_kernel(
    const float* __restrict__ Wf, const float* __restrict__ Wg,
    const float* __restrict__ Wh, short* __restrict__ WallT)
{
    int t = blockIdx.x * 256 + threadIdx.x;   // 0..98303
    int n = t >> 8;
    int k = t & 255;
    float v;
    if (n < 64)       v = Wf[k * 64 + n];
    else if (n < 128) v = Wg[k * 64 + (n - 64)];
    else              v = Wh[k * 256 + (n - 128)];
    WallT[n * 256 + k] = f2bf(v);
}

// ---------------------------------------------------------------------------
// Kernel 2: projections. 512 blocks x 128 threads (2 waves), 32 pixels/block.
//   GEMM1: fg[p][0:128] = x @ [Wf|Wg] + [bf|bg]   (bf16, row-major, stride 128)
//   GEMM2: hT[b][c][n]  = (x @ Wh + bh)^T          (bf16, V^T layout for attn)
// ---------------------------------------------------------------------------
#define XQ_STRIDE 264   // 256 + 8 pad

__global__ __launch_bounds__(128) void proj_kernel(
    const float* __restrict__ x, const short* __restrict__ WallT,
    const float* __restrict__ bfv, const float* __restrict__ bgv,
    const float* __restrict__ bhv,
    short* __restrict__ fg, short* __restrict__ hT)
{
    __shared__ short xq[32 * XQ_STRIDE];   // ~16.9 KB
    const int tid  = threadIdx.x;
    const int lane = tid & 63, w = tid >> 6;        // w in {0,1}
    const int quad = lane >> 4, l15 = lane & 15;
    const int p0 = blockIdx.x * 32;

    // stage x (fp32) -> bf16 LDS tile [32][256]
    {
        int r = tid >> 2, q = tid & 3;              // r 0..31
        const float* src = x + (size_t)(p0 + r) * 256 + q * 64;
        short* dst = xq + r * XQ_STRIDE + q * 64;
        for (int i = 0; i < 16; ++i) {
            f32x4 v = *(const f32x4*)(src + i * 4);
            s16x4 o;
            o[0] = f2bf(v[0]); o[1] = f2bf(v[1]); o[2] = f2bf(v[2]); o[3] = f2bf(v[3]);
            *(s16x4*)(dst + i * 4) = o;
        }
    }
    __syncthreads();

    // GEMM1: wave w owns pixel rows w*16..w*16+15, all 128 f|g cols
    {
        s16x8 af[8];
        const short* arow = xq + (w * 16 + l15) * XQ_STRIDE + quad * 8;
        for (int kk = 0; kk < 8; ++kk) af[kk] = *(const s16x8*)(arow + kk * 32);
        for (int nt = 0; nt < 8; ++nt) {
            f32x4 acc = {0.f, 0.f, 0.f, 0.f};
            const short* brow = WallT + (nt * 16 + l15) * 256 + quad * 8;
            for (int kk = 0; kk < 8; ++kk) {
                s16x8 bfr = *(const s16x8*)(brow + kk * 32);
                acc = __builtin_amdgcn_mfma_f32_16x16x32_bf16(af[kk], bfr, acc, 0, 0, 0);
            }
            int n = nt * 16 + l15;
            float bias = (n < 64) ? bfv[n] : bgv[n - 64];
            for (int r = 0; r < 4; ++r) {
                int p = p0 + w * 16 + quad * 4 + r;      // C/D: row=quad*4+r, col=l15
                fg[(size_t)p * 128 + n] = f2bf(acc[r] + bias);
            }
        }
    }

    // GEMM2: D[c][p] = sum_k Wh[k][c] * x[p][k]; wave w owns c in [w*128, w*128+128)
    {
        for (int pt = 0; pt < 2; ++pt) {
            s16x8 bb[8];
            const short* brow = xq + (pt * 16 + l15) * XQ_STRIDE + quad * 8;
            for (int kk = 0; kk < 8; ++kk) bb[kk] = *(const s16x8*)(brow + kk * 32);
            for (int mt = 0; mt < 8; ++mt) {
                f32x4 acc = {0.f, 0.f, 0.f, 0.f};
                const short* arow = WallT + (size_t)(128 + w * 128 + mt * 16 + l15) * 256 + quad * 8;
                for (int kk = 0; kk < 8; ++kk) {
                    s16x8 aa = *(const s16x8*)(arow + kk * 32);
                    acc = __builtin_amdgcn_mfma_f32_16x16x32_bf16(aa, bb[kk], acc, 0, 0, 0);
                }
                int p  = p0 + pt * 16 + l15;
                int bt = p >> 12, npix = p & 4095;
                for (int r = 0; r < 4; ++r) {
                    int c = w * 128 + mt * 16 + quad * 4 + r;
                    hT[(size_t)(bt * 256 + c) * 4096 + npix] = f2bf(acc[r] + bhv[c]);
                }
            }
        }
    }
}

// ---------------------------------------------------------------------------
// Kernel 3: flash attention, channel-split x2, key-split x nseg (flash split-K).
// Grid: 4 batches * 64 q-tiles * 2 channel-halves * nseg = 512*nseg blocks.
// nseg=2: each block does 2048 keys -> 1024 blocks -> 4 blocks/CU (LDS 36.9KB*4
// = 147.5KB <= 160KB), doubling resident waves vs the grid-capped 2 blocks/CU.
// Partials (unnormalized O bf16, m/l fp32) merged by merge_kernel.
// nseg=1 (workspace fallback): original fused residual epilogue.
// ---------------------------------------------------------------------------
#define KV_STRIDE 72    // 64 + 8 pad

__global__ __launch_bounds__(256) void attn_kernel(
    const short* __restrict__ fg, const short* __restrict__ hT,
    const float* __restrict__ xin, const float* __restrict__ scale_p,
    float* __restrict__ out,
    short* __restrict__ Op, float* __restrict__ mP, float* __restrict__ lP,
    int nseg)
{
    __shared__ short Klds[64 * KV_STRIDE];        //  9.2 KB
    __shared__ short Vlds[128 * KV_STRIDE];       // 18.4 KB (channel half)
    __shared__ short Plds[4 * 16 * KV_STRIDE];    //  9.2 KB (per-wave slices)

    const int tid  = threadIdx.x;
    const int lane = tid & 63, w = tid >> 6;
    const int quad = lane >> 4, l15 = lane & 15;
    const int seg = blockIdx.x >> 9;              // key segment
    const int inner = blockIdx.x & 511;
    const int b   = inner >> 7;                   // batch
    const int rem = inner & 127;
    const int q0  = (rem >> 1) * 64;              // query tile base
    const int ch0 = (rem & 1) * 128;              // channel half base

    // persistent Q A-fragments (g = cols 64..127 of fg); A[m=l15][k=quad*8+j]
    const short* qptr = fg + (size_t)(b * 4096 + q0 + w * 16 + l15) * 128 + 64 + quad * 8;
    s16x8 qf0 = *(const s16x8*)(qptr);
    s16x8 qf1 = *(const s16x8*)(qptr + 32);

    float m_r[4], l_r[4];
    f32x4 oacc[8];
    const f32x4 zac = {0.f, 0.f, 0.f, 0.f};
    for (int r = 0; r < 4; ++r) { m_r[r] = -INFINITY; l_r[r] = 0.f; }
    for (int ct = 0; ct < 8; ++ct) oacc[ct] = zac;

    const int segkeys = 4096 / nseg;
    const int k0 = seg * segkeys, k1 = k0 + segkeys;

    for (int m0 = k0; m0 < k1; m0 += 64) {
        // stage K tile (f = cols 0..63 of fg)
        for (int i = 0; i < 2; ++i) {
            int cid = tid + i * 256;
            int row = cid >> 3, segi = cid & 7;
            *(s16x8*)(Klds + row * KV_STRIDE + segi * 8) =
                *(const s16x8*)(fg + (size_t)(b * 4096 + m0 + row) * 128 + segi * 8);
        }
        // stage V^T tile: rows = channels ch0..ch0+127, cols = keys m0..m0+63
        for (int i = 0; i < 4; ++i) {
            int cid = tid + i * 256;
            int row = cid >> 3, segi = cid & 7;
            *(s16x8*)(Vlds + row * KV_STRIDE + segi * 8) =
                *(const s16x8*)(hT + (size_t)(b * 256 + ch0 + row) * 4096 + m0 + segi * 8);
        }
        __syncthreads();

        // S[q][key]: 16 q-rows x 64 keys per wave
        f32x4 s[4];
        __builtin_amdgcn_s_setprio(1);
        for (int nt = 0; nt < 4; ++nt) {
            const short* kp = Klds + (nt * 16 + l15) * KV_STRIDE + quad * 8;
            s16x8 kb0 = *(const s16x8*)(kp);
            s16x8 kb1 = *(const s16x8*)(kp + 32);
            f32x4 z = zac;
            z     = __builtin_amdgcn_mfma_f32_16x16x32_bf16(qf0, kb0, z, 0, 0, 0);
            s[nt] = __builtin_amdgcn_mfma_f32_16x16x32_bf16(qf1, kb1, z, 0, 0, 0);
        }
        __builtin_amdgcn_s_setprio(0);

        // online softmax; C/D layout: col=l15 (key), row=quad*4+r (query)
        for (int r = 0; r < 4; ++r) {
            float mx = fmaxf(fmaxf(s[0][r], s[1][r]), fmaxf(s[2][r], s[3][r]));
            mx = fmaxf(mx, __shfl_xor(mx, 1, 64));
            mx = fmaxf(mx, __shfl_xor(mx, 2, 64));
            mx = fmaxf(mx, __shfl_xor(mx, 4, 64));
            mx = fmaxf(mx, __shfl_xor(mx, 8, 64));
            float mn = fmaxf(m_r[r], mx);
            float alpha = __expf(m_r[r] - mn);
            m_r[r] = mn;
            float sum = 0.f;
            float p0v = __expf(s[0][r] - mn); s[0][r] = p0v; sum += p0v;
            float p1v = __expf(s[1][r] - mn); s[1][r] = p1v; sum += p1v;
            float p2v = __expf(s[2][r] - mn); s[2][r] = p2v; sum += p2v;
            float p3v = __expf(s[3][r] - mn); s[3][r] = p3v; sum += p3v;
            sum += __shfl_xor(sum, 1, 64);
            sum += __shfl_xor(sum, 2, 64);
            sum += __shfl_xor(sum, 4, 64);
            sum += __shfl_xor(sum, 8, 64);
            l_r[r] = l_r[r] * alpha + sum;
            for (int ct = 0; ct < 8; ++ct) oacc[ct][r] *= alpha;
            short* prow = Plds + (w * 16 + quad * 4 + r) * KV_STRIDE + l15;
            prow[0]  = f2bf(s[0][r]);
            prow[16] = f2bf(s[1][r]);
            prow[32] = f2bf(s[2][r]);
            prow[48] = f2bf(s[3][r]);
        }

        // O += P V over 128 channels: P A-frag from LDS; B-frag = V^T rows
        const short* pp = Plds + (w * 16 + l15) * KV_STRIDE + quad * 8;
        s16x8 pa0 = *(const s16x8*)(pp);
        s16x8 pa1 = *(const s16x8*)(pp + 32);
        __builtin_amdgcn_s_setprio(1);
        for (int ct = 0; ct < 8; ++ct) {
            const short* vp = Vlds + (ct * 16 + l15) * KV_STRIDE + quad * 8;
            s16x8 vb0 = *(const s16x8*)(vp);
            s16x8 vb1 = *(const s16x8*)(vp + 32);
            oacc[ct] = __builtin_amdgcn_mfma_f32_16x16x32_bf16(pa0, vb0, oacc[ct], 0, 0, 0);
            oacc[ct] = __builtin_amdgcn_mfma_f32_16x16x32_bf16(pa1, vb1, oacc[ct], 0, 0, 0);
        }
        __builtin_amdgcn_s_setprio(0);
        __syncthreads();
    }

    if (nseg == 1) {
        // fused epilogue: y = scale * (O / l) + x   (channels ch0..ch0+127 only)
        const float scale = *scale_p;
        float linv[4];
        for (int r = 0; r < 4; ++r) linv[r] = 1.f / l_r[r];
        for (int ct = 0; ct < 8; ++ct) {
            for (int r = 0; r < 4; ++r) {
                int p = b * 4096 + q0 + w * 16 + quad * 4 + r;
                size_t idx = (size_t)p * 256 + ch0 + ct * 16 + l15;
                out[idx] = scale * (oacc[ct][r] * linv[r]) + xin[idx];
            }
        }
    } else {
        // write unnormalized partial O (bf16) + per-query m,l (fp32)
        for (int ct = 0; ct < 8; ++ct) {
            for (int r = 0; r < 4; ++r) {
                int p = b * 4096 + q0 + w * 16 + quad * 4 + r;
                size_t idx = ((size_t)(seg * 16384 + p)) * 256 + ch0 + ct * 16 + l15;
                Op[idx] = f2bf(oacc[ct][r]);
            }
        }
        if (ch0 == 0 && l15 == 0) {   // one writer per query (ch-half 0, lane col 0)
            for (int r = 0; r < 4; ++r) {
                int p = b * 4096 + q0 + w * 16 + quad * 4 + r;
                mP[seg * 16384 + p] = m_r[r];
                lP[seg * 16384 + p] = l_r[r];
            }
        }
    }
}

// ---------------------------------------------------------------------------
// Kernel 4: merge 2 key-segments + residual epilogue (streaming, ~50MB).
// y = scale * (e1*O1 + e2*O2) / (e1*l1 + e2*l2) + x,  e_s = exp(m_s - max(m)).
// ---------------------------------------------------------------------------
__global__ __launch_bounds__(256) void merge_kernel(
    const short* __restrict__ Op, const float* __restrict__ mP,
    const float* __restrict__ lP, const float* __restrict__ xin,
    const float* __restrict__ scale_p, float* __restrict__ out)
{
    int t = blockIdx.x * 256 + threadIdx.x;       // 0..524287
    int p  = t >> 5;                               // global pixel 0..16383
    int c0 = (t & 31) * 8;                         // 8 channels / thread
    float m1 = mP[p], m2 = mP[16384 + p];
    float l1 = lP[p], l2 = lP[16384 + p];
    float M  = fmaxf(m1, m2);
    float e1 = __expf(m1 - M), e2 = __expf(m2 - M);
    float Linv = 1.f / (l1 * e1 + l2 * e2);
    float sc = *scale_p;
    float f1 = sc * e1 * Linv, f2 = sc * e2 * Linv;

    size_t idx = ((size_t)p << 8) + c0;
    s16x8 o1 = *(const s16x8*)(Op + idx);
    s16x8 o2 = *(const s16x8*)(Op + ((size_t)16384 << 8) + idx);
    f32x4 x0 = *(const f32x4*)(xin + idx);
    f32x4 x1 = *(const f32x4*)(xin + idx + 4);
    f32x4 y0, y1;
    for (int i = 0; i < 4; ++i) {
        y0[i] = f1 * bf2f(o1[i]) + f2 * bf2f(o2[i]) + x0[i];
        y1[i] = f1 * bf2f(o1[i + 4]) + f2 * bf2f(o2[i + 4]) + x1[i];
    }
    *(f32x4*)(out + idx) = y0;
    *(f32x4*)(out + idx + 4) = y1;
}

// ---------------------------------------------------------------------------
extern "C" void kernel_launch(void* const* d_in, const int* in_sizes, int n_in,
                              void* d_out, int out_size, void* d_ws, size_t ws_size,
                              hipStream_t stream) {
    (void)in_sizes; (void)n_in; (void)out_size;
    const float* x     = (const float*)d_in[0];
    const float* Wf    = (const float*)d_in[1];
    const float* bfv   = (const float*)d_in[2];
    const float* Wg    = (const float*)d_in[3];
    const float* bgv   = (const float*)d_in[4];
    const float* Wh    = (const float*)d_in[5];
    const float* bhv   = (const float*)d_in[6];
    const float* scale = (const float*)d_in[7];
    float* out = (float*)d_out;

    // workspace layout (bf16 as short)
    short* WallT = (short*)d_ws;                       // 384*256
    short* fg    = WallT + 384 * 256;                  // 16384*128
    short* hT    = fg + 16384 * 128;                   // 4*256*4096
    short* Op    = hT + (size_t)4 * 256 * 4096;        // 2*16384*256 (split-K partials)
    float* mP    = (float*)(Op + (size_t)2 * 16384 * 256);
    float* lP    = mP + 2 * 16384;
    size_t need2 = (size_t)((char*)(lP + 2 * 16384) - (char*)d_ws);  // ~29.8 MB
    int nseg = (ws_size >= need2) ? 2 : 1;

    wconv_kernel<<<384, 256, 0, stream>>>(Wf, Wg, Wh, WallT);
    proj_kernel<<<512, 128, 0, stream>>>(x, WallT, bfv, bgv, bhv, fg, hT);
    attn_kernel<<<512 * nseg, 256, 0, stream>>>(fg, hT, x, scale, out, Op, mP, lP, nseg);
    if (nseg == 2)
        merge_kernel<<<2048, 256, 0, stream>>>(Op, mP, lP, x, scale, out);
}

// Round 2
// 220.657 us; speedup vs baseline: 1.1921x; 1.1921x over previous
//
#include <hip/hip_runtime.h>
#include <math.h>

typedef float f32x4 __attribute__((ext_vector_type(4)));
typedef short s16x8 __attribute__((ext_vector_type(8)));
typedef short s16x4 __attribute__((ext_vector_type(4)));

__device__ inline short f2bf(float f) {
    unsigned u = __float_as_uint(f);
    u = (u + 0x7fffu + ((u >> 16) & 1u)) >> 16;  // RNE
    return (short)(unsigned short)u;
}
__device__ inline float bf2f(short s) {
    return __uint_as_float(((unsigned)(unsigned short)s) << 16);
}

// ---------------------------------------------------------------------------
// Kernel 1: pack weights -> WallT[n][k] bf16, n in [0,384) = f|g|h cols, k in [0,256)
// ---------------------------------------------------------------------------
__global__ __launch_bounds__(256) void wconv_kernel(
    const float* __restrict__ Wf, const float* __restrict__ Wg,
    const float* __restrict__ Wh, short* __restrict__ WallT)
{
    int t = blockIdx.x * 256 + threadIdx.x;   // 0..98303
    int n = t >> 8;
    int k = t & 255;
    float v;
    if (n < 64)       v = Wf[k * 64 + n];
    else if (n < 128) v = Wg[k * 64 + (n - 64)];
    else              v = Wh[k * 256 + (n - 128)];
    WallT[n * 256 + k] = f2bf(v);
}

// ---------------------------------------------------------------------------
// Kernel 2: projections. 512 blocks x 128 threads (2 waves), 32 pixels/block.
//   GEMM1: fg[p][0:128] = x @ [Wf|Wg] + [bf|bg]   (bf16, row-major, stride 128)
//   GEMM2: hT[b][c][n]  = (x @ Wh + bh)^T          (bf16, V^T layout for attn)
// ---------------------------------------------------------------------------
#define XQ_STRIDE 264   // 256 + 8 pad

__global__ __launch_bounds__(128) void proj_kernel(
    const float* __restrict__ x, const short* __restrict__ WallT,
    const float* __restrict__ bfv, const float* __restrict__ bgv,
    const float* __restrict__ bhv,
    short* __restrict__ fg, short* __restrict__ hT)
{
    __shared__ short xq[32 * XQ_STRIDE];   // ~16.9 KB
    const int tid  = threadIdx.x;
    const int lane = tid & 63, w = tid >> 6;        // w in {0,1}
    const int quad = lane >> 4, l15 = lane & 15;
    const int p0 = blockIdx.x * 32;

    // stage x (fp32) -> bf16 LDS tile [32][256]
    {
        int r = tid >> 2, q = tid & 3;              // r 0..31
        const float* src = x + (size_t)(p0 + r) * 256 + q * 64;
        short* dst = xq + r * XQ_STRIDE + q * 64;
        for (int i = 0; i < 16; ++i) {
            f32x4 v = *(const f32x4*)(src + i * 4);
            s16x4 o;
            o[0] = f2bf(v[0]); o[1] = f2bf(v[1]); o[2] = f2bf(v[2]); o[3] = f2bf(v[3]);
            *(s16x4*)(dst + i * 4) = o;
        }
    }
    __syncthreads();

    // GEMM1: wave w owns pixel rows w*16..w*16+15, all 128 f|g cols
    {
        s16x8 af[8];
        const short* arow = xq + (w * 16 + l15) * XQ_STRIDE + quad * 8;
        for (int kk = 0; kk < 8; ++kk) af[kk] = *(const s16x8*)(arow + kk * 32);
        for (int nt = 0; nt < 8; ++nt) {
            f32x4 acc = {0.f, 0.f, 0.f, 0.f};
            const short* brow = WallT + (nt * 16 + l15) * 256 + quad * 8;
            for (int kk = 0; kk < 8; ++kk) {
                s16x8 bfr = *(const s16x8*)(brow + kk * 32);
                acc = __builtin_amdgcn_mfma_f32_16x16x32_bf16(af[kk], bfr, acc, 0, 0, 0);
            }
            int n = nt * 16 + l15;
            float bias = (n < 64) ? bfv[n] : bgv[n - 64];
            for (int r = 0; r < 4; ++r) {
                int p = p0 + w * 16 + quad * 4 + r;      // C/D: row=quad*4+r, col=l15
                fg[(size_t)p * 128 + n] = f2bf(acc[r] + bias);
            }
        }
    }

    // GEMM2: D[c][p] = sum_k Wh[k][c] * x[p][k]; wave w owns c in [w*128, w*128+128)
    {
        for (int pt = 0; pt < 2; ++pt) {
            s16x8 bb[8];
            const short* brow = xq + (pt * 16 + l15) * XQ_STRIDE + quad * 8;
            for (int kk = 0; kk < 8; ++kk) bb[kk] = *(const s16x8*)(brow + kk * 32);
            for (int mt = 0; mt < 8; ++mt) {
                f32x4 acc = {0.f, 0.f, 0.f, 0.f};
                const short* arow = WallT + (size_t)(128 + w * 128 + mt * 16 + l15) * 256 + quad * 8;
                for (int kk = 0; kk < 8; ++kk) {
                    s16x8 aa = *(const s16x8*)(arow + kk * 32);
                    acc = __builtin_amdgcn_mfma_f32_16x16x32_bf16(aa, bb[kk], acc, 0, 0, 0);
                }
                int p  = p0 + pt * 16 + l15;
                int bt = p >> 12, npix = p & 4095;
                for (int r = 0; r < 4; ++r) {
                    int c = w * 128 + mt * 16 + quad * 4 + r;
                    hT[(size_t)(bt * 256 + c) * 4096 + npix] = f2bf(acc[r] + bhv[c]);
                }
            }
        }
    }
}

// ---------------------------------------------------------------------------
// Kernel 3: flash attention, channel-split x2, key-split x nseg (flash split-K).
// Round-2 changes vs round-1:
//  * swapped QK^T: S^T = mfma(K,Q) -> each lane holds 16 key-scores of ONE
//    query (q=l15) in registers; softmax max/sum = in-reg tree + 2 shfl_xor
//    (was 4x8 serialized shuffles). P written as 4x ds_write_b64 (was 16x b16).
//  * KV_STRIDE 72->64 + XOR swizzle seg^(row&7) on K/V/P: conflict-free
//    ds_read_b128 (was ~8-way, 1.36e7 conflict cycles). LDS 36864->32768 B.
// ---------------------------------------------------------------------------
#define KV_STRIDE 64

__global__ __launch_bounds__(256) void attn_kernel(
    const short* __restrict__ fg, const short* __restrict__ hT,
    const float* __restrict__ xin, const float* __restrict__ scale_p,
    float* __restrict__ out,
    short* __restrict__ Op, float* __restrict__ mP, float* __restrict__ lP,
    int nseg)
{
    __shared__ short Klds[64 * KV_STRIDE];        //  8 KB
    __shared__ short Vlds[128 * KV_STRIDE];       // 16 KB (channel half)
    __shared__ short Plds[64 * KV_STRIDE];        //  8 KB

    const int tid  = threadIdx.x;
    const int lane = tid & 63, w = tid >> 6;
    const int quad = lane >> 4, l15 = lane & 15;
    const int c7   = l15 & 7;                     // row-swizzle key for reads
    const int sw0  = (quad ^ c7) * 8;             // 16B-block offsets (shorts)
    const int sw1  = ((quad + 4) ^ c7) * 8;
    const int seg = blockIdx.x >> 9;              // key segment
    const int inner = blockIdx.x & 511;
    const int b   = inner >> 7;                   // batch
    const int rem = inner & 127;
    const int q0  = (rem >> 1) * 64;              // query tile base
    const int ch0 = (rem & 1) * 128;              // channel half base

    // persistent Q B-fragments (g = cols 64..127 of fg); B[k=quad*8+j][n=l15]
    const short* qptr = fg + (size_t)(b * 4096 + q0 + w * 16 + l15) * 128 + 64 + quad * 8;
    s16x8 qf0 = *(const s16x8*)(qptr);
    s16x8 qf1 = *(const s16x8*)(qptr + 32);

    float m_s = -INFINITY, l_s = 0.f;             // per-lane query = w*16+l15
    f32x4 oacc[8];
    const f32x4 zac = {0.f, 0.f, 0.f, 0.f};
    for (int ct = 0; ct < 8; ++ct) oacc[ct] = zac;

    const int segkeys = 4096 / nseg;
    const int k0 = seg * segkeys, k1 = k0 + segkeys;

    for (int m0 = k0; m0 < k1; m0 += 64) {
        // stage K tile (f = cols 0..63 of fg), swizzled
        for (int i = 0; i < 2; ++i) {
            int cid = tid + i * 256;
            int row = cid >> 3, sg = cid & 7;
            *(s16x8*)(Klds + row * KV_STRIDE + ((sg ^ (row & 7)) * 8)) =
                *(const s16x8*)(fg + (size_t)(b * 4096 + m0 + row) * 128 + sg * 8);
        }
        // stage V^T tile: rows = channels ch0..ch0+127, cols = keys m0..m0+63
        for (int i = 0; i < 4; ++i) {
            int cid = tid + i * 256;
            int row = cid >> 3, sg = cid & 7;
            *(s16x8*)(Vlds + row * KV_STRIDE + ((sg ^ (row & 7)) * 8)) =
                *(const s16x8*)(hT + (size_t)(b * 256 + ch0 + row) * 4096 + m0 + sg * 8);
        }
        __syncthreads();

        // S^T: s[nt][r] = score(key = m0+nt*16+quad*4+r, query = w*16+l15)
        f32x4 s[4];
        __builtin_amdgcn_s_setprio(1);
        for (int nt = 0; nt < 4; ++nt) {
            const short* kp = Klds + (nt * 16 + l15) * KV_STRIDE;
            s16x8 kb0 = *(const s16x8*)(kp + sw0);
            s16x8 kb1 = *(const s16x8*)(kp + sw1);
            f32x4 z = zac;
            z     = __builtin_amdgcn_mfma_f32_16x16x32_bf16(kb0, qf0, z, 0, 0, 0);
            s[nt] = __builtin_amdgcn_mfma_f32_16x16x32_bf16(kb1, qf1, z, 0, 0, 0);
        }
        __builtin_amdgcn_s_setprio(0);

        // in-register online softmax (16 scores/lane, reduce over quads)
        float mx0 = fmaxf(fmaxf(s[0][0], s[0][1]), fmaxf(s[0][2], s[0][3]));
        float mx1 = fmaxf(fmaxf(s[1][0], s[1][1]), fmaxf(s[1][2], s[1][3]));
        float mx2 = fmaxf(fmaxf(s[2][0], s[2][1]), fmaxf(s[2][2], s[2][3]));
        float mx3 = fmaxf(fmaxf(s[3][0], s[3][1]), fmaxf(s[3][2], s[3][3]));
        float mx = fmaxf(fmaxf(mx0, mx1), fmaxf(mx2, mx3));
        mx = fmaxf(mx, __shfl_xor(mx, 16, 64));
        mx = fmaxf(mx, __shfl_xor(mx, 32, 64));
        float mn = fmaxf(m_s, mx);
        float alpha = __expf(m_s - mn);
        m_s = mn;
        float sum = 0.f;
        for (int nt = 0; nt < 4; ++nt)
            for (int r = 0; r < 4; ++r) {
                float p = __expf(s[nt][r] - mn);
                s[nt][r] = p;
                sum += p;
            }
        sum += __shfl_xor(sum, 16, 64);
        sum += __shfl_xor(sum, 32, 64);
        l_s = l_s * alpha + sum;

        // write P row (query w*16+l15): keys nt*16+quad*4+{0..3}, swizzled b64
        {
            short* prow = Plds + (w * 16 + l15) * KV_STRIDE;
            int h4 = (quad & 1) * 4;
            for (int nt = 0; nt < 4; ++nt) {
                s16x4 pk;
                pk[0] = f2bf(s[nt][0]); pk[1] = f2bf(s[nt][1]);
                pk[2] = f2bf(s[nt][2]); pk[3] = f2bf(s[nt][3]);
                int cb = 2 * nt + (quad >> 1);
                *(s16x4*)(prow + ((cb ^ c7) * 8) + h4) = pk;
            }
        }

        // rescale O by alpha of query quad*4+r (transpose via bpermute)
        {
            float a0 = __shfl(alpha, quad * 4 + 0, 64);
            float a1 = __shfl(alpha, quad * 4 + 1, 64);
            float a2 = __shfl(alpha, quad * 4 + 2, 64);
            float a3 = __shfl(alpha, quad * 4 + 3, 64);
            for (int ct = 0; ct < 8; ++ct) {
                oacc[ct][0] *= a0; oacc[ct][1] *= a1;
                oacc[ct][2] *= a2; oacc[ct][3] *= a3;
            }
        }

        // O += P V over 128 channels: P A-frag from LDS; B-frag = V^T rows
        const short* pp = Plds + (w * 16 + l15) * KV_STRIDE;
        s16x8 pa0 = *(const s16x8*)(pp + sw0);
        s16x8 pa1 = *(const s16x8*)(pp + sw1);
        __builtin_amdgcn_s_setprio(1);
        for (int ct = 0; ct < 8; ++ct) {
            const short* vp = Vlds + (ct * 16 + l15) * KV_STRIDE;
            s16x8 vb0 = *(const s16x8*)(vp + sw0);
            s16x8 vb1 = *(const s16x8*)(vp + sw1);
            oacc[ct] = __builtin_amdgcn_mfma_f32_16x16x32_bf16(pa0, vb0, oacc[ct], 0, 0, 0);
            oacc[ct] = __builtin_amdgcn_mfma_f32_16x16x32_bf16(pa1, vb1, oacc[ct], 0, 0, 0);
        }
        __builtin_amdgcn_s_setprio(0);
        __syncthreads();
    }

    if (nseg == 1) {
        // fused epilogue: y = scale * (O / l) + x   (channels ch0..ch0+127 only)
        const float scale = *scale_p;
        float linv[4];
        for (int r = 0; r < 4; ++r) {
            float lq = __shfl(l_s, quad * 4 + r, 64);
            linv[r] = 1.f / lq;
        }
        for (int ct = 0; ct < 8; ++ct) {
            for (int r = 0; r < 4; ++r) {
                int p = b * 4096 + q0 + w * 16 + quad * 4 + r;
                size_t idx = (size_t)p * 256 + ch0 + ct * 16 + l15;
                out[idx] = scale * (oacc[ct][r] * linv[r]) + xin[idx];
            }
        }
    } else {
        // write unnormalized partial O (bf16) + per-query m,l (fp32)
        for (int ct = 0; ct < 8; ++ct) {
            for (int r = 0; r < 4; ++r) {
                int p = b * 4096 + q0 + w * 16 + quad * 4 + r;
                size_t idx = ((size_t)(seg * 16384 + p)) * 256 + ch0 + ct * 16 + l15;
                Op[idx] = f2bf(oacc[ct][r]);
            }
        }
        if (ch0 == 0 && quad == 0) {   // one writer per query (lane l15 owns it)
            int p = b * 4096 + q0 + w * 16 + l15;
            mP[seg * 16384 + p] = m_s;
            lP[seg * 16384 + p] = l_s;
        }
    }
}

// ---------------------------------------------------------------------------
// Kernel 4: merge 2 key-segments + residual epilogue (streaming, ~50MB).
// y = scale * (e1*O1 + e2*O2) / (e1*l1 + e2*l2) + x,  e_s = exp(m_s - max(m)).
// ---------------------------------------------------------------------------
__global__ __launch_bounds__(256) void merge_kernel(
    const short* __restrict__ Op, const float* __restrict__ mP,
    const float* __restrict__ lP, const float* __restrict__ xin,
    const float* __restrict__ scale_p, float* __restrict__ out)
{
    int t = blockIdx.x * 256 + threadIdx.x;       // 0..524287
    int p  = t >> 5;                               // global pixel 0..16383
    int c0 = (t & 31) * 8;                         // 8 channels / thread
    float m1 = mP[p], m2 = mP[16384 + p];
    float l1 = lP[p], l2 = lP[16384 + p];
    float M  = fmaxf(m1, m2);
    float e1 = __expf(m1 - M), e2 = __expf(m2 - M);
    float Linv = 1.f / (l1 * e1 + l2 * e2);
    float sc = *scale_p;
    float f1 = sc * e1 * Linv, f2 = sc * e2 * Linv;

    size_t idx = ((size_t)p << 8) + c0;
    s16x8 o1 = *(const s16x8*)(Op + idx);
    s16x8 o2 = *(const s16x8*)(Op + ((size_t)16384 << 8) + idx);
    f32x4 x0 = *(const f32x4*)(xin + idx);
    f32x4 x1 = *(const f32x4*)(xin + idx + 4);
    f32x4 y0, y1;
    for (int i = 0; i < 4; ++i) {
        y0[i] = f1 * bf2f(o1[i]) + f2 * bf2f(o2[i]) + x0[i];
        y1[i] = f1 * bf2f(o1[i + 4]) + f2 * bf2f(o2[i + 4]) + x1[i];
    }
    *(f32x4*)(out + idx) = y0;
    *(f32x4*)(out + idx + 4) = y1;
}

// ---------------------------------------------------------------------------
extern "C" void kernel_launch(void* const* d_in, const int* in_sizes, int n_in,
                              void* d_out, int out_size, void* d_ws, size_t ws_size,
                              hipStream_t stream) {
    (void)in_sizes; (void)n_in; (void)out_size;
    const float* x     = (const float*)d_in[0];
    const float* Wf    = (const float*)d_in[1];
    const float* bfv   = (const float*)d_in[2];
    const float* Wg    = (const float*)d_in[3];
    const float* bgv   = (const float*)d_in[4];
    const float* Wh    = (const float*)d_in[5];
    const float* bhv   = (const float*)d_in[6];
    const float* scale = (const float*)d_in[7];
    float* out = (float*)d_out;

    // workspace layout (bf16 as short)
    short* WallT = (short*)d_ws;                       // 384*256
    short* fg    = WallT + 384 * 256;                  // 16384*128
    short* hT    = fg + 16384 * 128;                   // 4*256*4096
    short* Op    = hT + (size_t)4 * 256 * 4096;        // 2*16384*256 (split-K partials)
    float* mP    = (float*)(Op + (size_t)2 * 16384 * 256);
    float* lP    = mP + 2 * 16384;
    size_t need2 = (size_t)((char*)(lP + 2 * 16384) - (char*)d_ws);  // ~29.8 MB
    int nseg = (ws_size >= need2) ? 2 : 1;

    wconv_kernel<<<384, 256, 0, stream>>>(Wf, Wg, Wh, WallT);
    proj_kernel<<<512, 128, 0, stream>>>(x, WallT, bfv, bgv, bhv, fg, hT);
    attn_kernel<<<512 * nseg, 256, 0, stream>>>(fg, hT, x, scale, out, Op, mP, lP, nseg);
    if (nseg == 2)
        merge_kernel<<<2048, 256, 0, stream>>>(Op, mP, lP, x, scale, out);
}

// Round 3
// 211.692 us; speedup vs baseline: 1.2426x; 1.0423x over previous
//
#include <hip/hip_runtime.h>
#include <math.h>

typedef float f32x4 __attribute__((ext_vector_type(4)));
typedef short s16x8 __attribute__((ext_vector_type(8)));
typedef short s16x4 __attribute__((ext_vector_type(4)));

__device__ inline short f2bf(float f) {
    unsigned u = __float_as_uint(f);
    u = (u + 0x7fffu + ((u >> 16) & 1u)) >> 16;  // RNE
    return (short)(unsigned short)u;
}
__device__ inline float bf2f(short s) {
    return __uint_as_float(((unsigned)(unsigned short)s) << 16);
}

// ---------------------------------------------------------------------------
// Kernel 1: pack weights -> WallT[n][k] bf16, n in [0,384) = f|g|h cols, k in [0,256)
// ---------------------------------------------------------------------------
__global__ __launch_bounds__(256) void wconv_kernel(
    const float* __restrict__ Wf, const float* __restrict__ Wg,
    const float* __restrict__ Wh, short* __restrict__ WallT)
{
    int t = blockIdx.x * 256 + threadIdx.x;   // 0..98303
    int n = t >> 8;
    int k = t & 255;
    float v;
    if (n < 64)       v = Wf[k * 64 + n];
    else if (n < 128) v = Wg[k * 64 + (n - 64)];
    else              v = Wh[k * 256 + (n - 128)];
    WallT[n * 256 + k] = f2bf(v);
}

// ---------------------------------------------------------------------------
// Kernel 2: projections. Round-3: 1024 blocks x 256 threads (4 waves),
// 16 pixels/block -> 4 blocks/CU x 4 waves = 16 waves/CU (was 1 wave/SIMD).
//   GEMM1: fg[p][0:128] = x @ [Wf|Wg] + [bf|bg]   (wave w owns cols w*32..+31)
//   GEMM2: hT[b][c][n]  = (x @ Wh + bh)^T          (wave w owns chans w*64..+63)
// x-tile fragment af[] serves as GEMM1 A-frag (m=l15=pixel) AND GEMM2 B-frag
// (n=l15=pixel) -- identical per-lane layout.
// ---------------------------------------------------------------------------
#define XQ_STRIDE 264   // 256 + 8 pad

__global__ __launch_bounds__(256) void proj_kernel(
    const float* __restrict__ x, const short* __restrict__ WallT,
    const float* __restrict__ bfv, const float* __restrict__ bgv,
    const float* __restrict__ bhv,
    short* __restrict__ fg, short* __restrict__ hT)
{
    __shared__ short xq[16 * XQ_STRIDE];   // ~8.4 KB
    const int tid  = threadIdx.x;
    const int lane = tid & 63, w = tid >> 6;        // w in {0..3}
    const int quad = lane >> 4, l15 = lane & 15;
    const int p0 = blockIdx.x * 16;

    // stage x (fp32) -> bf16 LDS tile [16][256]
    {
        int r = tid >> 4, cs = tid & 15;            // r 0..15, 16 cols/thread
        const float* src = x + (size_t)(p0 + r) * 256 + cs * 16;
        short* dst = xq + r * XQ_STRIDE + cs * 16;
        for (int j = 0; j < 4; ++j) {
            f32x4 v = *(const f32x4*)(src + j * 4);
            s16x4 o;
            o[0] = f2bf(v[0]); o[1] = f2bf(v[1]); o[2] = f2bf(v[2]); o[3] = f2bf(v[3]);
            *(s16x4*)(dst + j * 4) = o;
        }
    }
    __syncthreads();

    // x-tile fragments: rows = the 16 pixels (l15), k = quad*8 + kk*32
    s16x8 af[8];
    {
        const short* arow = xq + l15 * XQ_STRIDE + quad * 8;
        for (int kk = 0; kk < 8; ++kk) af[kk] = *(const s16x8*)(arow + kk * 32);
    }

    // GEMM1: wave w owns fg cols w*32 .. w*32+31
    for (int ntl = 0; ntl < 2; ++ntl) {
        int nt = w * 2 + ntl;
        f32x4 acc = {0.f, 0.f, 0.f, 0.f};
        const short* brow = WallT + (nt * 16 + l15) * 256 + quad * 8;
        for (int kk = 0; kk < 8; ++kk) {
            s16x8 bfr = *(const s16x8*)(brow + kk * 32);
            acc = __builtin_amdgcn_mfma_f32_16x16x32_bf16(af[kk], bfr, acc, 0, 0, 0);
        }
        int n = nt * 16 + l15;
        float bias = (n < 64) ? bfv[n] : bgv[n - 64];
        for (int r = 0; r < 4; ++r) {
            int p = p0 + quad * 4 + r;               // C/D: row=quad*4+r, col=l15
            fg[(size_t)p * 128 + n] = f2bf(acc[r] + bias);
        }
    }

    // GEMM2: wave w owns channels w*64 .. w*64+63; D[c][p], col = l15 = pixel
    for (int mtl = 0; mtl < 4; ++mtl) {
        f32x4 acc = {0.f, 0.f, 0.f, 0.f};
        const short* arow = WallT + (size_t)(128 + w * 64 + mtl * 16 + l15) * 256 + quad * 8;
        for (int kk = 0; kk < 8; ++kk) {
            s16x8 aa = *(const s16x8*)(arow + kk * 32);
            acc = __builtin_amdgcn_mfma_f32_16x16x32_bf16(aa, af[kk], acc, 0, 0, 0);
        }
        int p  = p0 + l15;
        int bt = p >> 12, npix = p & 4095;
        for (int r = 0; r < 4; ++r) {
            int c = w * 64 + mtl * 16 + quad * 4 + r;
            hT[(size_t)(bt * 256 + c) * 4096 + npix] = f2bf(acc[r] + bhv[c]);
        }
    }
}

// ---------------------------------------------------------------------------
// Kernel 3: flash attention, channel-split x2, key-split x nseg.
// Round-3 changes vs round-2:
//  * T14 async-STAGE: K/V tile t+1 global loads issued into registers right
//    after barrier B of tile t; vmcnt drain + ds_write happen at tile t+1's
//    barrier A. Load latency hides under QK/softmax/PV instead of sitting
//    between the barriers. LDS stays 32 KB single-buffered.
//  * T13 defer-max: skip O-rescale (+4 shfl +32 mul) when per-tile max grew
//    by <= 8 (exact math: P bounded by e^8, bf16-safe; merge unaffected).
// ---------------------------------------------------------------------------
#define KV_STRIDE 64

__global__ __launch_bounds__(256) void attn_kernel(
    const short* __restrict__ fg, const short* __restrict__ hT,
    const float* __restrict__ xin, const float* __restrict__ scale_p,
    float* __restrict__ out,
    short* __restrict__ Op, float* __restrict__ mP, float* __restrict__ lP,
    int nseg)
{
    __shared__ short Klds[64 * KV_STRIDE];        //  8 KB
    __shared__ short Vlds[128 * KV_STRIDE];       // 16 KB (channel half)
    __shared__ short Plds[64 * KV_STRIDE];        //  8 KB

    const int tid  = threadIdx.x;
    const int lane = tid & 63, w = tid >> 6;
    const int quad = lane >> 4, l15 = lane & 15;
    const int c7   = l15 & 7;                     // row-swizzle key for reads
    const int sw0  = (quad ^ c7) * 8;             // 16B-block offsets (shorts)
    const int sw1  = ((quad + 4) ^ c7) * 8;
    const int seg = blockIdx.x >> 9;              // key segment
    const int inner = blockIdx.x & 511;
    const int b   = inner >> 7;                   // batch
    const int rem = inner & 127;
    const int q0  = (rem >> 1) * 64;              // query tile base
    const int ch0 = (rem & 1) * 128;              // channel half base

    // persistent Q B-fragments (g = cols 64..127 of fg); B[k=quad*8+j][n=l15]
    const short* qptr = fg + (size_t)(b * 4096 + q0 + w * 16 + l15) * 128 + 64 + quad * 8;
    s16x8 qf0 = *(const s16x8*)(qptr);
    s16x8 qf1 = *(const s16x8*)(qptr + 32);

    // staging geometry: thread owns rows (tid>>3)+32i, byte-seg tid&7
    const int srow = tid >> 3, ssg = tid & 7;
    const short* kg = fg + (size_t)b * 4096 * 128 + (size_t)srow * 128 + ssg * 8;
    const short* vg = hT + ((size_t)(b * 256 + ch0) + srow) * 4096 + ssg * 8;
    const int swz = ((ssg ^ (srow & 7)) * 8);     // invariant under row+32
    short* kw = Klds + srow * KV_STRIDE + swz;
    short* vw = Vlds + srow * KV_STRIDE + swz;

    s16x8 kreg0, kreg1, vreg0, vreg1, vreg2, vreg3;
    auto issue = [&](int m0) {
        kreg0 = *(const s16x8*)(kg + (size_t)m0 * 128);
        kreg1 = *(const s16x8*)(kg + (size_t)(m0 + 32) * 128);
        vreg0 = *(const s16x8*)(vg + m0);
        vreg1 = *(const s16x8*)(vg + m0 + 32 * 4096);
        vreg2 = *(const s16x8*)(vg + m0 + 64 * 4096);
        vreg3 = *(const s16x8*)(vg + m0 + 96 * 4096);
    };

    float m_s = -INFINITY, l_s = 0.f;             // per-lane query = w*16+l15
    f32x4 oacc[8];
    const f32x4 zac = {0.f, 0.f, 0.f, 0.f};
    for (int ct = 0; ct < 8; ++ct) oacc[ct] = zac;

    const int segkeys = 4096 / nseg;
    const int k0 = seg * segkeys, k1 = k0 + segkeys;

    issue(k0);
    for (int m0 = k0; m0 < k1; m0 += 64) {
        __syncthreads();                          // barrier A: prev readers done; drains vmcnt
        *(s16x8*)(kw)           = kreg0;
        *(s16x8*)(kw + 32 * KV_STRIDE) = kreg1;
        *(s16x8*)(vw)           = vreg0;
        *(s16x8*)(vw + 32 * KV_STRIDE) = vreg1;
        *(s16x8*)(vw + 64 * KV_STRIDE) = vreg2;
        *(s16x8*)(vw + 96 * KV_STRIDE) = vreg3;
        __syncthreads();                          // barrier B: K/V tile visible
        if (m0 + 64 < k1) issue(m0 + 64);         // prefetch hides under compute

        // S^T: s[nt][r] = score(key = m0+nt*16+quad*4+r, query = w*16+l15)
        f32x4 s[4];
        __builtin_amdgcn_s_setprio(1);
        for (int nt = 0; nt < 4; ++nt) {
            const short* kp = Klds + (nt * 16 + l15) * KV_STRIDE;
            s16x8 kb0 = *(const s16x8*)(kp + sw0);
            s16x8 kb1 = *(const s16x8*)(kp + sw1);
            f32x4 z = zac;
            z     = __builtin_amdgcn_mfma_f32_16x16x32_bf16(kb0, qf0, z, 0, 0, 0);
            s[nt] = __builtin_amdgcn_mfma_f32_16x16x32_bf16(kb1, qf1, z, 0, 0, 0);
        }
        __builtin_amdgcn_s_setprio(0);

        // in-register online softmax (16 scores/lane, reduce over quads)
        float mx0 = fmaxf(fmaxf(s[0][0], s[0][1]), fmaxf(s[0][2], s[0][3]));
        float mx1 = fmaxf(fmaxf(s[1][0], s[1][1]), fmaxf(s[1][2], s[1][3]));
        float mx2 = fmaxf(fmaxf(s[2][0], s[2][1]), fmaxf(s[2][2], s[2][3]));
        float mx3 = fmaxf(fmaxf(s[3][0], s[3][1]), fmaxf(s[3][2], s[3][3]));
        float mx = fmaxf(fmaxf(mx0, mx1), fmaxf(mx2, mx3));
        mx = fmaxf(mx, __shfl_xor(mx, 16, 64));
        mx = fmaxf(mx, __shfl_xor(mx, 32, 64));   // per-query max, replicated x4

        // T13 defer-max: only rescale when the max actually grew materially
        if (__any(mx > m_s + 8.f)) {
            float mn = fmaxf(m_s, mx);
            float alpha = __expf(m_s - mn);
            m_s = mn;
            l_s *= alpha;
            float a0 = __shfl(alpha, quad * 4 + 0, 64);
            float a1 = __shfl(alpha, quad * 4 + 1, 64);
            float a2 = __shfl(alpha, quad * 4 + 2, 64);
            float a3 = __shfl(alpha, quad * 4 + 3, 64);
            for (int ct = 0; ct < 8; ++ct) {
                oacc[ct][0] *= a0; oacc[ct][1] *= a1;
                oacc[ct][2] *= a2; oacc[ct][3] *= a3;
            }
        }
        float sum = 0.f;
        for (int nt = 0; nt < 4; ++nt)
            for (int r = 0; r < 4; ++r) {
                float p = __expf(s[nt][r] - m_s);
                s[nt][r] = p;
                sum += p;
            }
        sum += __shfl_xor(sum, 16, 64);
        sum += __shfl_xor(sum, 32, 64);
        l_s += sum;

        // write P row (query w*16+l15): keys nt*16+quad*4+{0..3}, swizzled b64
        {
            short* prow = Plds + (w * 16 + l15) * KV_STRIDE;
            int h4 = (quad & 1) * 4;
            for (int nt = 0; nt < 4; ++nt) {
                s16x4 pk;
                pk[0] = f2bf(s[nt][0]); pk[1] = f2bf(s[nt][1]);
                pk[2] = f2bf(s[nt][2]); pk[3] = f2bf(s[nt][3]);
                int cb = 2 * nt + (quad >> 1);
                *(s16x4*)(prow + ((cb ^ c7) * 8) + h4) = pk;
            }
        }

        // O += P V over 128 channels: P A-frag from LDS; B-frag = V^T rows
        const short* pp = Plds + (w * 16 + l15) * KV_STRIDE;
        s16x8 pa0 = *(const s16x8*)(pp + sw0);
        s16x8 pa1 = *(const s16x8*)(pp + sw1);
        __builtin_amdgcn_s_setprio(1);
        for (int ct = 0; ct < 8; ++ct) {
            const short* vp = Vlds + (ct * 16 + l15) * KV_STRIDE;
            s16x8 vb0 = *(const s16x8*)(vp + sw0);
            s16x8 vb1 = *(const s16x8*)(vp + sw1);
            oacc[ct] = __builtin_amdgcn_mfma_f32_16x16x32_bf16(pa0, vb0, oacc[ct], 0, 0, 0);
            oacc[ct] = __builtin_amdgcn_mfma_f32_16x16x32_bf16(pa1, vb1, oacc[ct], 0, 0, 0);
        }
        __builtin_amdgcn_s_setprio(0);
    }

    if (nseg == 1) {
        // fused epilogue: y = scale * (O / l) + x   (channels ch0..ch0+127 only)
        const float scale = *scale_p;
        float linv[4];
        for (int r = 0; r < 4; ++r) {
            float lq = __shfl(l_s, quad * 4 + r, 64);
            linv[r] = 1.f / lq;
        }
        for (int ct = 0; ct < 8; ++ct) {
            for (int r = 0; r < 4; ++r) {
                int p = b * 4096 + q0 + w * 16 + quad * 4 + r;
                size_t idx = (size_t)p * 256 + ch0 + ct * 16 + l15;
                out[idx] = scale * (oacc[ct][r] * linv[r]) + xin[idx];
            }
        }
    } else {
        // write unnormalized partial O (bf16) + per-query m,l (fp32)
        for (int ct = 0; ct < 8; ++ct) {
            for (int r = 0; r < 4; ++r) {
                int p = b * 4096 + q0 + w * 16 + quad * 4 + r;
                size_t idx = ((size_t)(seg * 16384 + p)) * 256 + ch0 + ct * 16 + l15;
                Op[idx] = f2bf(oacc[ct][r]);
            }
        }
        if (ch0 == 0 && quad == 0) {   // one writer per query (lane l15 owns it)
            int p = b * 4096 + q0 + w * 16 + l15;
            mP[seg * 16384 + p] = m_s;
            lP[seg * 16384 + p] = l_s;
        }
    }
}

// ---------------------------------------------------------------------------
// Kernel 4: merge 2 key-segments + residual epilogue (streaming, ~50MB).
// y = scale * (e1*O1 + e2*O2) / (e1*l1 + e2*l2) + x,  e_s = exp(m_s - max(m)).
// ---------------------------------------------------------------------------
__global__ __launch_bounds__(256) void merge_kernel(
    const short* __restrict__ Op, const float* __restrict__ mP,
    const float* __restrict__ lP, const float* __restrict__ xin,
    const float* __restrict__ scale_p, float* __restrict__ out)
{
    int t = blockIdx.x * 256 + threadIdx.x;       // 0..524287
    int p  = t >> 5;                               // global pixel 0..16383
    int c0 = (t & 31) * 8;                         // 8 channels / thread
    float m1 = mP[p], m2 = mP[16384 + p];
    float l1 = lP[p], l2 = lP[16384 + p];
    float M  = fmaxf(m1, m2);
    float e1 = __expf(m1 - M), e2 = __expf(m2 - M);
    float Linv = 1.f / (l1 * e1 + l2 * e2);
    float sc = *scale_p;
    float f1 = sc * e1 * Linv, f2 = sc * e2 * Linv;

    size_t idx = ((size_t)p << 8) + c0;
    s16x8 o1 = *(const s16x8*)(Op + idx);
    s16x8 o2 = *(const s16x8*)(Op + ((size_t)16384 << 8) + idx);
    f32x4 x0 = *(const f32x4*)(xin + idx);
    f32x4 x1 = *(const f32x4*)(xin + idx + 4);
    f32x4 y0, y1;
    for (int i = 0; i < 4; ++i) {
        y0[i] = f1 * bf2f(o1[i]) + f2 * bf2f(o2[i]) + x0[i];
        y1[i] = f1 * bf2f(o1[i + 4]) + f2 * bf2f(o2[i + 4]) + x1[i];
    }
    *(f32x4*)(out + idx) = y0;
    *(f32x4*)(out + idx + 4) = y1;
}

// ---------------------------------------------------------------------------
extern "C" void kernel_launch(void* const* d_in, const int* in_sizes, int n_in,
                              void* d_out, int out_size, void* d_ws, size_t ws_size,
                              hipStream_t stream) {
    (void)in_sizes; (void)n_in; (void)out_size;
    const float* x     = (const float*)d_in[0];
    const float* Wf    = (const float*)d_in[1];
    const float* bfv   = (const float*)d_in[2];
    const float* Wg    = (const float*)d_in[3];
    const float* bgv   = (const float*)d_in[4];
    const float* Wh    = (const float*)d_in[5];
    const float* bhv   = (const float*)d_in[6];
    const float* scale = (const float*)d_in[7];
    float* out = (float*)d_out;

    // workspace layout (bf16 as short)
    short* WallT = (short*)d_ws;                       // 384*256
    short* fg    = WallT + 384 * 256;                  // 16384*128
    short* hT    = fg + 16384 * 128;                   // 4*256*4096
    short* Op    = hT + (size_t)4 * 256 * 4096;        // 2*16384*256 (split-K partials)
    float* mP    = (float*)(Op + (size_t)2 * 16384 * 256);
    float* lP    = mP + 2 * 16384;
    size_t need2 = (size_t)((char*)(lP + 2 * 16384) - (char*)d_ws);  // ~29.8 MB
    int nseg = (ws_size >= need2) ? 2 : 1;

    wconv_kernel<<<384, 256, 0, stream>>>(Wf, Wg, Wh, WallT);
    proj_kernel<<<1024, 256, 0, stream>>>(x, WallT, bfv, bgv, bhv, fg, hT);
    attn_kernel<<<512 * nseg, 256, 0, stream>>>(fg, hT, x, scale, out, Op, mP, lP, nseg);
    if (nseg == 2)
        merge_kernel<<<2048, 256, 0, stream>>>(Op, mP, lP, x, scale, out);
}

// Round 4
// 193.954 us; speedup vs baseline: 1.3562x; 1.0915x over previous
//
#include <hip/hip_runtime.h>
#include <math.h>

typedef float f32x4 __attribute__((ext_vector_type(4)));
typedef short s16x8 __attribute__((ext_vector_type(8)));
typedef short s16x4 __attribute__((ext_vector_type(4)));
typedef int   i32x2 __attribute__((ext_vector_type(2)));

__device__ inline short f2bf(float f) {
    unsigned u = __float_as_uint(f);
    u = (u + 0x7fffu + ((u >> 16) & 1u)) >> 16;  // RNE
    return (short)(unsigned short)u;
}
__device__ inline float bf2f(short s) {
    return __uint_as_float(((unsigned)(unsigned short)s) << 16);
}
__device__ inline unsigned cvt_pk_bf16(float lo, float hi) {
    unsigned d;
    asm("v_cvt_pk_bf16_f32 %0, %1, %2" : "=v"(d) : "v"(lo), "v"(hi));
    return d;   // [15:0]=bf16(lo), [31:16]=bf16(hi)
}

// ---------------------------------------------------------------------------
// Kernel 1: pack weights -> WallT[n][k] bf16, n in [0,384) = f|g|h cols, k in [0,256)
// ---------------------------------------------------------------------------
__global__ __launch_bounds__(256) void wconv_kernel(
    const float* __restrict__ Wf, const float* __restrict__ Wg,
    const float* __restrict__ Wh, short* __restrict__ WallT)
{
    int t = blockIdx.x * 256 + threadIdx.x;   // 0..98303
    int n = t >> 8;
    int k = t & 255;
    float v;
    if (n < 64)       v = Wf[k * 64 + n];
    else if (n < 128) v = Wg[k * 64 + (n - 64)];
    else              v = Wh[k * 256 + (n - 128)];
    WallT[n * 256 + k] = f2bf(v);
}

// ---------------------------------------------------------------------------
// Kernel 2: projections. 1024 blocks x 256 threads (4 waves), 16 pixels/block.
//   GEMM1: fg[p][0:128] = x @ [Wf|Wg] + [bf|bg]   (wave w owns cols w*32..+31)
//   GEMM2: hT[b][c][n]  = (x @ Wh + bh)^T          (wave w owns chans w*64..+63)
// ---------------------------------------------------------------------------
#define XQ_STRIDE 264   // 256 + 8 pad

__global__ __launch_bounds__(256) void proj_kernel(
    const float* __restrict__ x, const short* __restrict__ WallT,
    const float* __restrict__ bfv, const float* __restrict__ bgv,
    const float* __restrict__ bhv,
    short* __restrict__ fg, short* __restrict__ hT)
{
    __shared__ short xq[16 * XQ_STRIDE];   // ~8.4 KB
    const int tid  = threadIdx.x;
    const int lane = tid & 63, w = tid >> 6;        // w in {0..3}
    const int quad = lane >> 4, l15 = lane & 15;
    const int p0 = blockIdx.x * 16;

    // stage x (fp32) -> bf16 LDS tile [16][256]
    {
        int r = tid >> 4, cs = tid & 15;            // r 0..15, 16 cols/thread
        const float* src = x + (size_t)(p0 + r) * 256 + cs * 16;
        short* dst = xq + r * XQ_STRIDE + cs * 16;
        for (int j = 0; j < 4; ++j) {
            f32x4 v = *(const f32x4*)(src + j * 4);
            s16x4 o;
            o[0] = f2bf(v[0]); o[1] = f2bf(v[1]); o[2] = f2bf(v[2]); o[3] = f2bf(v[3]);
            *(s16x4*)(dst + j * 4) = o;
        }
    }
    __syncthreads();

    // x-tile fragments: rows = the 16 pixels (l15), k = quad*8 + kk*32
    s16x8 af[8];
    {
        const short* arow = xq + l15 * XQ_STRIDE + quad * 8;
        for (int kk = 0; kk < 8; ++kk) af[kk] = *(const s16x8*)(arow + kk * 32);
    }

    // GEMM1: wave w owns fg cols w*32 .. w*32+31
    for (int ntl = 0; ntl < 2; ++ntl) {
        int nt = w * 2 + ntl;
        f32x4 acc = {0.f, 0.f, 0.f, 0.f};
        const short* brow = WallT + (nt * 16 + l15) * 256 + quad * 8;
        for (int kk = 0; kk < 8; ++kk) {
            s16x8 bfr = *(const s16x8*)(brow + kk * 32);
            acc = __builtin_amdgcn_mfma_f32_16x16x32_bf16(af[kk], bfr, acc, 0, 0, 0);
        }
        int n = nt * 16 + l15;
        float bias = (n < 64) ? bfv[n] : bgv[n - 64];
        for (int r = 0; r < 4; ++r) {
            int p = p0 + quad * 4 + r;               // C/D: row=quad*4+r, col=l15
            fg[(size_t)p * 128 + n] = f2bf(acc[r] + bias);
        }
    }

    // GEMM2: wave w owns channels w*64 .. w*64+63; D[c][p], col = l15 = pixel
    for (int mtl = 0; mtl < 4; ++mtl) {
        f32x4 acc = {0.f, 0.f, 0.f, 0.f};
        const short* arow = WallT + (size_t)(128 + w * 64 + mtl * 16 + l15) * 256 + quad * 8;
        for (int kk = 0; kk < 8; ++kk) {
            s16x8 aa = *(const s16x8*)(arow + kk * 32);
            acc = __builtin_amdgcn_mfma_f32_16x16x32_bf16(aa, af[kk], acc, 0, 0, 0);
        }
        int p  = p0 + l15;
        int bt = p >> 12, npix = p & 4095;
        for (int r = 0; r < 4; ++r) {
            int c = w * 64 + mtl * 16 + quad * 4 + r;
            hT[(size_t)(bt * 256 + c) * 4096 + npix] = f2bf(acc[r] + bhv[c]);
        }
    }
}

// ---------------------------------------------------------------------------
// Kernel 3: flash attention, FULL 256 channels per block (round-4: channel
// split removed -> softmax computed ONCE per query tile, was duplicated 2x),
// key-split x nseg. Grid: 4 batches * 64 q-tiles * nseg = 256*nseg blocks.
// LDS: K 8KB + V 32KB + P 8KB = 48KB -> 3 blocks/CU LDS-cap.
//  * T14 async-STAGE: K/V tile t+1 -> regs during compute of tile t.
//  * T12 cvt_pk: P pack via v_cvt_pk_bf16_f32 (8 ops, was ~70 VALU f2bf).
//  * T13 defer-max; XOR-swizzled LDS; swapped QK^T in-register softmax.
// ---------------------------------------------------------------------------
#define KV_STRIDE 64

__global__ __launch_bounds__(256) void attn_kernel(
    const short* __restrict__ fg, const short* __restrict__ hT,
    const float* __restrict__ xin, const float* __restrict__ scale_p,
    float* __restrict__ out,
    short* __restrict__ Op, float* __restrict__ mP, float* __restrict__ lP,
    int nseg)
{
    __shared__ short Klds[64 * KV_STRIDE];        //  8 KB
    __shared__ short Vlds[256 * KV_STRIDE];       // 32 KB (all channels)
    __shared__ short Plds[64 * KV_STRIDE];        //  8 KB

    const int tid  = threadIdx.x;
    const int lane = tid & 63, w = tid >> 6;
    const int quad = lane >> 4, l15 = lane & 15;
    const int c7   = l15 & 7;                     // row-swizzle key for reads
    const int sw0  = (quad ^ c7) * 8;             // 16B-block offsets (shorts)
    const int sw1  = ((quad + 4) ^ c7) * 8;
    const int seg   = blockIdx.x >> 8;            // key segment
    const int inner = blockIdx.x & 255;
    const int b   = inner >> 6;                   // batch
    const int q0  = (inner & 63) * 64;            // query tile base

    // persistent Q B-fragments (g = cols 64..127 of fg); B[k=quad*8+j][n=l15]
    const short* qptr = fg + (size_t)(b * 4096 + q0 + w * 16 + l15) * 128 + 64 + quad * 8;
    s16x8 qf0 = *(const s16x8*)(qptr);
    s16x8 qf1 = *(const s16x8*)(qptr + 32);

    // staging geometry: thread owns rows (tid>>3)+32i, byte-seg tid&7
    const int srow = tid >> 3, ssg = tid & 7;
    const short* kg = fg + (size_t)b * 4096 * 128 + (size_t)srow * 128 + ssg * 8;
    const short* vg = hT + ((size_t)b * 256 + srow) * 4096 + ssg * 8;
    const int swz = ((ssg ^ (srow & 7)) * 8);     // invariant under row+32
    short* kw = Klds + srow * KV_STRIDE + swz;
    short* vw = Vlds + srow * KV_STRIDE + swz;

    s16x8 kreg0, kreg1;
    s16x8 vreg0, vreg1, vreg2, vreg3, vreg4, vreg5, vreg6, vreg7;
    auto issue = [&](int m0) {
        kreg0 = *(const s16x8*)(kg + (size_t)m0 * 128);
        kreg1 = *(const s16x8*)(kg + (size_t)(m0 + 32) * 128);
        vreg0 = *(const s16x8*)(vg + m0);
        vreg1 = *(const s16x8*)(vg + m0 + (size_t)32 * 4096);
        vreg2 = *(const s16x8*)(vg + m0 + (size_t)64 * 4096);
        vreg3 = *(const s16x8*)(vg + m0 + (size_t)96 * 4096);
        vreg4 = *(const s16x8*)(vg + m0 + (size_t)128 * 4096);
        vreg5 = *(const s16x8*)(vg + m0 + (size_t)160 * 4096);
        vreg6 = *(const s16x8*)(vg + m0 + (size_t)192 * 4096);
        vreg7 = *(const s16x8*)(vg + m0 + (size_t)224 * 4096);
    };

    float m_s = -INFINITY, l_s = 0.f;             // per-lane query = w*16+l15
    f32x4 oacc[16];
    const f32x4 zac = {0.f, 0.f, 0.f, 0.f};
    for (int ct = 0; ct < 16; ++ct) oacc[ct] = zac;

    const int segkeys = 4096 / nseg;
    const int k0 = seg * segkeys, k1 = k0 + segkeys;

    issue(k0);
    for (int m0 = k0; m0 < k1; m0 += 64) {
        __syncthreads();                          // barrier A: prev readers done
        *(s16x8*)(kw)                    = kreg0;
        *(s16x8*)(kw +  32 * KV_STRIDE)  = kreg1;
        *(s16x8*)(vw)                    = vreg0;
        *(s16x8*)(vw +  32 * KV_STRIDE)  = vreg1;
        *(s16x8*)(vw +  64 * KV_STRIDE)  = vreg2;
        *(s16x8*)(vw +  96 * KV_STRIDE)  = vreg3;
        *(s16x8*)(vw + 128 * KV_STRIDE)  = vreg4;
        *(s16x8*)(vw + 160 * KV_STRIDE)  = vreg5;
        *(s16x8*)(vw + 192 * KV_STRIDE)  = vreg6;
        *(s16x8*)(vw + 224 * KV_STRIDE)  = vreg7;
        __syncthreads();                          // barrier B: K/V tile visible
        if (m0 + 64 < k1) issue(m0 + 64);         // prefetch hides under compute

        // S^T: s[nt][r] = score(key = m0+nt*16+quad*4+r, query = w*16+l15)
        f32x4 s[4];
        __builtin_amdgcn_s_setprio(1);
        for (int nt = 0; nt < 4; ++nt) {
            const short* kp = Klds + (nt * 16 + l15) * KV_STRIDE;
            s16x8 kb0 = *(const s16x8*)(kp + sw0);
            s16x8 kb1 = *(const s16x8*)(kp + sw1);
            f32x4 z = zac;
            z     = __builtin_amdgcn_mfma_f32_16x16x32_bf16(kb0, qf0, z, 0, 0, 0);
            s[nt] = __builtin_amdgcn_mfma_f32_16x16x32_bf16(kb1, qf1, z, 0, 0, 0);
        }
        __builtin_amdgcn_s_setprio(0);

        // in-register online softmax (16 scores/lane, reduce over quads)
        float mx0 = fmaxf(fmaxf(s[0][0], s[0][1]), fmaxf(s[0][2], s[0][3]));
        float mx1 = fmaxf(fmaxf(s[1][0], s[1][1]), fmaxf(s[1][2], s[1][3]));
        float mx2 = fmaxf(fmaxf(s[2][0], s[2][1]), fmaxf(s[2][2], s[2][3]));
        float mx3 = fmaxf(fmaxf(s[3][0], s[3][1]), fmaxf(s[3][2], s[3][3]));
        float mx = fmaxf(fmaxf(mx0, mx1), fmaxf(mx2, mx3));
        mx = fmaxf(mx, __shfl_xor(mx, 16, 64));
        mx = fmaxf(mx, __shfl_xor(mx, 32, 64));   // per-query max, replicated x4

        // T13 defer-max: only rescale when the max actually grew materially
        if (__any(mx > m_s + 8.f)) {
            float mn = fmaxf(m_s, mx);
            float alpha = __expf(m_s - mn);
            m_s = mn;
            l_s *= alpha;
            float a0 = __shfl(alpha, quad * 4 + 0, 64);
            float a1 = __shfl(alpha, quad * 4 + 1, 64);
            float a2 = __shfl(alpha, quad * 4 + 2, 64);
            float a3 = __shfl(alpha, quad * 4 + 3, 64);
            for (int ct = 0; ct < 16; ++ct) {
                oacc[ct][0] *= a0; oacc[ct][1] *= a1;
                oacc[ct][2] *= a2; oacc[ct][3] *= a3;
            }
        }
        float sum = 0.f;
        for (int nt = 0; nt < 4; ++nt)
            for (int r = 0; r < 4; ++r) {
                float p = __expf(s[nt][r] - m_s);
                s[nt][r] = p;
                sum += p;
            }
        sum += __shfl_xor(sum, 16, 64);
        sum += __shfl_xor(sum, 32, 64);
        l_s += sum;

        // write P row (query w*16+l15): keys nt*16+quad*4+{0..3}; cvt_pk + b64
        {
            short* prow = Plds + (w * 16 + l15) * KV_STRIDE;
            int h4 = (quad & 1) * 4;
            for (int nt = 0; nt < 4; ++nt) {
                i32x2 pk;
                pk[0] = (int)cvt_pk_bf16(s[nt][0], s[nt][1]);
                pk[1] = (int)cvt_pk_bf16(s[nt][2], s[nt][3]);
                int cb = 2 * nt + (quad >> 1);
                *(i32x2*)(prow + ((cb ^ c7) * 8) + h4) = pk;
            }
        }

        // O += P V over all 256 channels: P A-frag from LDS; B-frag = V^T rows
        const short* pp = Plds + (w * 16 + l15) * KV_STRIDE;
        s16x8 pa0 = *(const s16x8*)(pp + sw0);
        s16x8 pa1 = *(const s16x8*)(pp + sw1);
        __builtin_amdgcn_s_setprio(1);
        for (int ct = 0; ct < 16; ++ct) {
            const short* vp = Vlds + (ct * 16 + l15) * KV_STRIDE;
            s16x8 vb0 = *(const s16x8*)(vp + sw0);
            s16x8 vb1 = *(const s16x8*)(vp + sw1);
            oacc[ct] = __builtin_amdgcn_mfma_f32_16x16x32_bf16(pa0, vb0, oacc[ct], 0, 0, 0);
            oacc[ct] = __builtin_amdgcn_mfma_f32_16x16x32_bf16(pa1, vb1, oacc[ct], 0, 0, 0);
        }
        __builtin_amdgcn_s_setprio(0);
    }

    if (nseg == 1) {
        // fused epilogue: y = scale * (O / l) + x
        const float scale = *scale_p;
        float linv[4];
        for (int r = 0; r < 4; ++r) {
            float lq = __shfl(l_s, quad * 4 + r, 64);
            linv[r] = 1.f / lq;
        }
        for (int ct = 0; ct < 16; ++ct) {
            for (int r = 0; r < 4; ++r) {
                int p = b * 4096 + q0 + w * 16 + quad * 4 + r;
                size_t idx = (size_t)p * 256 + ct * 16 + l15;
                out[idx] = scale * (oacc[ct][r] * linv[r]) + xin[idx];
            }
        }
    } else {
        // write unnormalized partial O (bf16) + per-query m,l (fp32)
        for (int ct = 0; ct < 16; ++ct) {
            for (int r = 0; r < 4; ++r) {
                int p = b * 4096 + q0 + w * 16 + quad * 4 + r;
                size_t idx = ((size_t)(seg * 16384 + p)) * 256 + ct * 16 + l15;
                Op[idx] = f2bf(oacc[ct][r]);
            }
        }
        if (quad == 0) {                // lane l15 owns query w*16+l15
            int p = b * 4096 + q0 + w * 16 + l15;
            mP[seg * 16384 + p] = m_s;
            lP[seg * 16384 + p] = l_s;
        }
    }
}

// ---------------------------------------------------------------------------
// Kernel 4: merge nseg key-segments + residual epilogue (streaming).
// y = scale * (sum_s e_s*O_s) / (sum_s e_s*l_s) + x,  e_s = exp(m_s - max(m)).
// ---------------------------------------------------------------------------
__global__ __launch_bounds__(256) void merge_kernel(
    const short* __restrict__ Op, const float* __restrict__ mP,
    const float* __restrict__ lP, const float* __restrict__ xin,
    const float* __restrict__ scale_p, float* __restrict__ out, int nseg)
{
    int t = blockIdx.x * 256 + threadIdx.x;       // 0..524287
    int p  = t >> 5;                               // global pixel 0..16383
    int c0 = (t & 31) * 8;                         // 8 channels / thread

    float mv[4], lv[4];
    float M = -INFINITY;
    for (int s = 0; s < nseg; ++s) {
        mv[s] = mP[s * 16384 + p];
        lv[s] = lP[s * 16384 + p];
        M = fmaxf(M, mv[s]);
    }
    float denom = 0.f;
    float e[4];
    for (int s = 0; s < nseg; ++s) {
        e[s] = __expf(mv[s] - M);
        denom += lv[s] * e[s];
    }
    float sc = *scale_p;
    float Linv = sc / denom;

    size_t idx = ((size_t)p << 8) + c0;
    f32x4 y0 = *(const f32x4*)(xin + idx);
    f32x4 y1 = *(const f32x4*)(xin + idx + 4);
    for (int s = 0; s < nseg; ++s) {
        float fs = e[s] * Linv;
        s16x8 o = *(const s16x8*)(Op + ((size_t)(s * 16384) << 8) + idx);
        for (int i = 0; i < 4; ++i) {
            y0[i] += fs * bf2f(o[i]);
            y1[i] += fs * bf2f(o[i + 4]);
        }
    }
    *(f32x4*)(out + idx) = y0;
    *(f32x4*)(out + idx + 4) = y1;
}

// ---------------------------------------------------------------------------
extern "C" void kernel_launch(void* const* d_in, const int* in_sizes, int n_in,
                              void* d_out, int out_size, void* d_ws, size_t ws_size,
                              hipStream_t stream) {
    (void)in_sizes; (void)n_in; (void)out_size;
    const float* x     = (const float*)d_in[0];
    const float* Wf    = (const float*)d_in[1];
    const float* bfv   = (const float*)d_in[2];
    const float* Wg    = (const float*)d_in[3];
    const float* bgv   = (const float*)d_in[4];
    const float* Wh    = (const float*)d_in[5];
    const float* bhv   = (const float*)d_in[6];
    const float* scale = (const float*)d_in[7];
    float* out = (float*)d_out;

    // workspace layout (bf16 as short)
    const size_t base_shorts = (size_t)384 * 256 + (size_t)16384 * 128
                             + (size_t)4 * 256 * 4096;
    auto need = [&](int n) {
        return base_shorts * 2
             + (size_t)n * 16384 * 256 * 2        // Op
             + (size_t)n * 16384 * 4 * 2;         // mP + lP
    };
    int nseg = 1;
    if (ws_size >= need(4)) nseg = 4;
    else if (ws_size >= need(2)) nseg = 2;

    short* WallT = (short*)d_ws;                       // 384*256
    short* fg    = WallT + 384 * 256;                  // 16384*128
    short* hT    = fg + 16384 * 128;                   // 4*256*4096
    short* Op    = hT + (size_t)4 * 256 * 4096;        // nseg*16384*256
    float* mP    = (float*)(Op + (size_t)nseg * 16384 * 256);
    float* lP    = mP + (size_t)nseg * 16384;

    wconv_kernel<<<384, 256, 0, stream>>>(Wf, Wg, Wh, WallT);
    proj_kernel<<<1024, 256, 0, stream>>>(x, WallT, bfv, bgv, bhv, fg, hT);
    attn_kernel<<<256 * nseg, 256, 0, stream>>>(fg, hT, x, scale, out, Op, mP, lP, nseg);
    if (nseg > 1)
        merge_kernel<<<2048, 256, 0, stream>>>(Op, mP, lP, x, scale, out, nseg);
}